// Round 1
// baseline (95.137 us; speedup 1.0000x reference)
//
#include <hip/hip_runtime.h>
#include <math.h>

#define EPS   1e-6f
#define BB    256
#define NNEG  1000
#define HH    3
#define DD    128
#define NCN   250   // neg_im2cluster values are in [0, min(NUM_CLUSTER)) = [0,250)

// Single main kernel: centroid normalization is FUSED into the sim-table pass
// (dot and ||c||^2 accumulated together from the raw row-major centroids), so
// the old kA_prep transpose kernel and its scattered 384 KB of stores are gone.
// Each block writes its per-sample partial to d_ws[b]; a trivial 1-block
// reducer kernel produces the scalar (kernel boundary = cross-XCD visibility
// for free; no atomics, no out-zeroing dispatch needed).
//
// Block layout: 512 threads = 8 waves per sample b.
//  entry   : prefetch negc[b] -> LDS (HBM latency overlaps phase A)
//  phase A : se normalize + positive path (waves 0..2, centroid norm fused)
//  phase 3 : sim table. 16-lane group per cluster: lanes 0..15 read 32 B each
//            of one raw centroid row (512 B contiguous per group; adjacent
//            groups read adjacent rows -> 2 KB/wave/iter, L2-friendly),
//            accumulate dot AND ||c||^2, reduce with intra-group shfl_xor
//            (masks 1,2,4,8 never leave an aligned 16-lane group).
//  phase 4 : negative-path loss via LDS lookups
//  phase 5 : block reduce -> plain store of partial to d_ws[b]
__global__ __launch_bounds__(512) void kMain(
        const float* __restrict__ se,
        const float* __restrict__ c0,
        const float* __restrict__ c1,
        const float* __restrict__ c2,
        const int* __restrict__ i2c0,
        const int* __restrict__ i2c1,
        const int* __restrict__ i2c2,
        const int* __restrict__ index,
        const int* __restrict__ negc,
        float* __restrict__ partial) {
    int b = blockIdx.x;
    int tid = threadIdx.x, wave = tid >> 6, lane = tid & 63;

    __shared__ float sse[HH * DD];
    __shared__ float ssim[HH * NCN];
    __shared__ int   snegc[NNEG * HH];   // 12 KB
    __shared__ int   slab[HH];
    __shared__ float ph[HH];
    __shared__ float wL[8], wT[8];

    // --- prefetch this sample's negative labels into LDS ---
    {
        const int4* src = (const int4*)(negc + (size_t)b * (NNEG * HH));
        int4* dst = (int4*)snegc;
        #pragma unroll
        for (int i = tid; i < (NNEG * HH) / 4; i += 512) dst[i] = src[i];
    }

    // --- phase A: se normalize + positive path (waves 0..2) ---
    if (wave < HH) {
        int h = wave;
        const float2 s = *(const float2*)(se + (size_t)b * (HH * DD) + h * DD + lane * 2);
        float ssq = s.x * s.x + s.y * s.y;
        #pragma unroll
        for (int off = 32; off; off >>= 1) ssq += __shfl_xor(ssq, off);
        float inv = 1.0f / fmaxf(sqrtf(ssq), 1e-12f);
        float2 sn = make_float2(s.x * inv, s.y * inv);
        sse[h * DD + lane * 2]     = sn.x;
        sse[h * DD + lane * 2 + 1] = sn.y;

        int idx = index[b];
        const int*   ip = (h == 0) ? i2c0 : (h == 1) ? i2c1 : i2c2;
        const float* cp = (h == 0) ? c0   : (h == 1) ? c1   : c2;
        int cidx = ip[idx];
        const float2 cv = *(const float2*)(cp + (size_t)cidx * DD + lane * 2);
        float dot = sn.x * cv.x + sn.y * cv.y;
        float csq = cv.x * cv.x + cv.y * cv.y;
        #pragma unroll
        for (int off = 32; off; off >>= 1) {
            dot += __shfl_xor(dot, off);
            csq += __shfl_xor(csq, off);
        }
        if (lane == 0) {
            float invc = 1.0f / fmaxf(sqrtf(csq), 1e-12f);
            ph[h]   = (dot * invc + 1.0f) * 0.5f;
            slab[h] = cidx;
        }
    }
    __syncthreads();

    // --- phase 3: fused-normalization sim table ---
    // group g (0..31) handles clusters cl = g, g+32, ...; lane l (0..15)
    // owns d in [8l, 8l+8). se slices for all 3 hierarchies preloaded once.
    {
        int g = tid >> 4, l = tid & 15;
        float4 sa[HH], sb[HH];
        #pragma unroll
        for (int h = 0; h < HH; ++h) {
            const float4* p4 = (const float4*)(sse + h * DD);
            sa[h] = p4[l * 2];
            sb[h] = p4[l * 2 + 1];
        }
        #pragma unroll 4
        for (int it = 0; it < 23; ++it) {          // cl <= 735 < 750: no bound check
            int cl = g + 32 * it;
            int h = (cl >= 2 * NCN) ? 2 : (cl >= NCN ? 1 : 0);
            int c = cl - h * NCN;
            const float* cp = (h == 0) ? c0 : (h == 1) ? c1 : c2;
            const float4* row = (const float4*)(cp + (size_t)c * DD);
            float4 v0 = row[l * 2];
            float4 v1 = row[l * 2 + 1];
            float4 s0 = sa[h], s1 = sb[h];
            float dot = v0.x * s0.x;
            dot = fmaf(v0.y, s0.y, dot); dot = fmaf(v0.z, s0.z, dot); dot = fmaf(v0.w, s0.w, dot);
            dot = fmaf(v1.x, s1.x, dot); dot = fmaf(v1.y, s1.y, dot);
            dot = fmaf(v1.z, s1.z, dot); dot = fmaf(v1.w, s1.w, dot);
            float nrm = v0.x * v0.x;
            nrm = fmaf(v0.y, v0.y, nrm); nrm = fmaf(v0.z, v0.z, nrm); nrm = fmaf(v0.w, v0.w, nrm);
            nrm = fmaf(v1.x, v1.x, nrm); nrm = fmaf(v1.y, v1.y, nrm);
            nrm = fmaf(v1.z, v1.z, nrm); nrm = fmaf(v1.w, v1.w, nrm);
            #pragma unroll
            for (int off = 8; off; off >>= 1) {    // stays inside aligned 16-lane group
                dot += __shfl_xor(dot, off);
                nrm += __shfl_xor(nrm, off);
            }
            if (l == 0)
                ssim[cl] = (dot / fmaxf(sqrtf(nrm), 1e-12f) + 1.0f) * 0.5f;
        }
        if (g < 14) {                              // tail: cl = g + 736 < 750
            int cl = g + 736;                      // all in hierarchy 2
            int c = cl - 2 * NCN;
            const float4* row = (const float4*)(c2 + (size_t)c * DD);
            float4 v0 = row[l * 2];
            float4 v1 = row[l * 2 + 1];
            float4 s0 = sa[2], s1 = sb[2];
            float dot = v0.x * s0.x;
            dot = fmaf(v0.y, s0.y, dot); dot = fmaf(v0.z, s0.z, dot); dot = fmaf(v0.w, s0.w, dot);
            dot = fmaf(v1.x, s1.x, dot); dot = fmaf(v1.y, s1.y, dot);
            dot = fmaf(v1.z, s1.z, dot); dot = fmaf(v1.w, s1.w, dot);
            float nrm = v0.x * v0.x;
            nrm = fmaf(v0.y, v0.y, nrm); nrm = fmaf(v0.z, v0.z, nrm); nrm = fmaf(v0.w, v0.w, nrm);
            nrm = fmaf(v1.x, v1.x, nrm); nrm = fmaf(v1.y, v1.y, nrm);
            nrm = fmaf(v1.z, v1.z, nrm); nrm = fmaf(v1.w, v1.w, nrm);
            #pragma unroll
            for (int off = 8; off; off >>= 1) {
                dot += __shfl_xor(dot, off);
                nrm += __shfl_xor(nrm, off);
            }
            if (l == 0)
                ssim[cl] = (dot / fmaxf(sqrtf(nrm), 1e-12f) + 1.0f) * 0.5f;
        }
    }
    __syncthreads();

    // --- phase 4: negative-path loss ---
    int l0 = slab[0], l1 = slab[1], l2 = slab[2];
    float accL = 0.0f, accT = 0.0f;
    #pragma unroll
    for (int k = 0; k < NNEG / 512 + 1; ++k) {
        int n = tid + k * 512;
        if (n < NNEG) {
            int i0 = snegc[n * 3], i1 = snegc[n * 3 + 1], i2 = snegc[n * 3 + 2];
            float p = ssim[i0] * ssim[NCN + i1] * ssim[2 * NCN + i2];
            if (i0 != l0 || i1 != l1 || i2 != l2) {
                accL -= logf(1.0f - p + EPS);
                accT += 1.0f;
            }
        }
    }
    #pragma unroll
    for (int off = 32; off; off >>= 1) {
        accL += __shfl_xor(accL, off);
        accT += __shfl_xor(accT, off);
    }
    if (lane == 0) { wL[wave] = accL; wT[wave] = accT; }
    __syncthreads();

    // --- phase 5: combine, store per-block partial (no atomics, no init) ---
    if (tid == 0) {
        float L = 0.0f, T = 0.0f;
        #pragma unroll
        for (int w = 0; w < 8; ++w) { L += wL[w]; T += wT[w]; }
        float neg_b = L / (T + EPS);
        float pos_b = -logf(ph[0] * ph[1] * ph[2] + EPS);
        partial[b] = pos_b + neg_b;
    }
}

// Tiny reducer: sums the 256 per-block partials and writes the mean.
// Overwrites (not accumulates) out[0], so no zero-init dispatch is needed.
__global__ void kReduce(const float* __restrict__ partial, float* __restrict__ out) {
    int tid = threadIdx.x, wave = tid >> 6, lane = tid & 63;
    __shared__ float ws[4];
    float v = partial[tid];
    #pragma unroll
    for (int off = 32; off; off >>= 1) v += __shfl_xor(v, off);
    if (lane == 0) ws[wave] = v;
    __syncthreads();
    if (tid == 0)
        out[0] = (ws[0] + ws[1] + ws[2] + ws[3]) * (1.0f / (2.0f * BB));
}

extern "C" void kernel_launch(void* const* d_in, const int* in_sizes, int n_in,
                              void* d_out, int out_size, void* d_ws, size_t ws_size,
                              hipStream_t stream) {
    const float* se    = (const float*)d_in[0];
    const float* c0    = (const float*)d_in[1];
    const float* c1    = (const float*)d_in[2];
    const float* c2    = (const float*)d_in[3];
    const int*   i2c0  = (const int*)d_in[4];
    const int*   i2c1  = (const int*)d_in[5];
    const int*   i2c2  = (const int*)d_in[6];
    const int*   index = (const int*)d_in[7];
    const int*   negc  = (const int*)d_in[8];

    float* partial = (float*)d_ws;   // BB floats
    float* out     = (float*)d_out;

    hipLaunchKernelGGL(kMain, dim3(BB), dim3(512), 0, stream,
                       se, c0, c1, c2, i2c0, i2c1, i2c2, index, negc, partial);
    hipLaunchKernelGGL(kReduce, dim3(1), dim3(256), 0, stream,
                       partial, out);
}

// Round 3
// 92.374 us; speedup vs baseline: 1.0299x; 1.0299x over previous
//
#include <hip/hip_runtime.h>
#include <math.h>

#define EPS   1e-6f
#define BB    256
#define NNEG  1000
#define HH    3
#define DD    128
#define NCN   250   // neg_im2cluster values are in [0, min(NUM_CLUSTER)) = [0,250)

// R3 = resubmit of R2 (container-acquisition failure, not a kernel failure).
// Verified R0 structure: kA transpose+normalize once, kB thread-local dots.
// R1 proved the alternative (fused normalization, cross-lane reduce per
// cluster) is latency-bound at 1 block/CU and costs ~7 us vs ~2.5 us here.

// kA: normalize centroid rows 0..249 of each hierarchy into transposed
// [h][d][c] layout in d_ws; zero the scalar output. Kernel boundary (not a
// grid sync) hands centT to kB — cross-XCD visibility for free (grid.sync +
// threadfence measured ~65 us in an earlier session; a kernel boundary ~2 us).
__global__ __launch_bounds__(256) void kA_prep(const float* __restrict__ c0,
                        const float* __restrict__ c1,
                        const float* __restrict__ c2,
                        float* __restrict__ centT,
                        float* __restrict__ out) {
    if (blockIdx.x == 0 && threadIdx.x == 0) out[0] = 0.0f;
    int wid  = blockIdx.x * 4 + (threadIdx.x >> 6);
    int lane = threadIdx.x & 63;
    if (wid >= HH * NCN) return;
    int h = (wid >= 2 * NCN) ? 2 : (wid >= NCN ? 1 : 0);
    int c = wid - h * NCN;
    const float* cp = (h == 0) ? c0 : (h == 1) ? c1 : c2;
    const float2 v = *(const float2*)(cp + (size_t)c * DD + lane * 2);
    float ss = v.x * v.x + v.y * v.y;
    #pragma unroll
    for (int off = 32; off; off >>= 1) ss += __shfl_xor(ss, off);
    float inv = 1.0f / fmaxf(sqrtf(ss), 1e-12f);
    float* base = centT + h * (DD * NCN);
    base[(lane * 2)     * NCN + c] = v.x * inv;
    base[(lane * 2 + 1) * NCN + c] = v.y * inv;
}

// kB: one block (512 threads = 8 waves) per sample b.
//  entry : prefetch negc[b] -> LDS (HBM latency overlaps phase A)
//  phase A: se normalize + positive path (waves 0..2)
//  phase 3: sim table, 2 adjacent clusters per thread: one ds_read_b128 of
//           se feeds 8 FMAs (halves LDS-pipe pressure vs 1 cluster/thread),
//           float2 loads over adjacent clusters stay lane-coalesced
//           (512 B/instr). Dot products are THREAD-LOCAL: no cross-lane ops,
//           two independent FMA chains -> compiler pipelines loads freely.
//  phase 4: negative-path loss via LDS lookups
//  phase 5: block reduce + one atomicAdd
__global__ __launch_bounds__(512) void kB_main(
        const float* __restrict__ se,
        const float* __restrict__ c0,
        const float* __restrict__ c1,
        const float* __restrict__ c2,
        const int* __restrict__ i2c0,
        const int* __restrict__ i2c1,
        const int* __restrict__ i2c2,
        const int* __restrict__ index,
        const int* __restrict__ negc,
        const float* __restrict__ centT,
        float* __restrict__ out) {
    int b = blockIdx.x;
    int tid = threadIdx.x, wave = tid >> 6, lane = tid & 63;

    __shared__ float sse[HH * DD];
    __shared__ float ssim[HH * NCN];
    __shared__ int   snegc[NNEG * HH];   // 12 KB
    __shared__ int   slab[HH];
    __shared__ float ph[HH];
    __shared__ float wL[8], wT[8];

    // --- prefetch this sample's negative labels into LDS ---
    {
        const int4* src = (const int4*)(negc + (size_t)b * (NNEG * HH));
        int4* dst = (int4*)snegc;
        #pragma unroll
        for (int i = tid; i < (NNEG * HH) / 4; i += 512) dst[i] = src[i];
    }

    // --- phase A: se normalize + positive path (waves 0..2) ---
    if (wave < HH) {
        int h = wave;
        const float2 s = *(const float2*)(se + (size_t)b * (HH * DD) + h * DD + lane * 2);
        float ssq = s.x * s.x + s.y * s.y;
        #pragma unroll
        for (int off = 32; off; off >>= 1) ssq += __shfl_xor(ssq, off);
        float inv = 1.0f / fmaxf(sqrtf(ssq), 1e-12f);
        float2 sn = make_float2(s.x * inv, s.y * inv);
        sse[h * DD + lane * 2]     = sn.x;
        sse[h * DD + lane * 2 + 1] = sn.y;

        int idx = index[b];
        const int*   ip = (h == 0) ? i2c0 : (h == 1) ? i2c1 : i2c2;
        const float* cp = (h == 0) ? c0   : (h == 1) ? c1   : c2;
        int cidx = ip[idx];
        const float2 cv = *(const float2*)(cp + (size_t)cidx * DD + lane * 2);
        float dot = sn.x * cv.x + sn.y * cv.y;
        float csq = cv.x * cv.x + cv.y * cv.y;
        #pragma unroll
        for (int off = 32; off; off >>= 1) {
            dot += __shfl_xor(dot, off);
            csq += __shfl_xor(csq, off);
        }
        if (lane == 0) {
            float invc = 1.0f / fmaxf(sqrtf(csq), 1e-12f);
            ph[h]   = (dot * invc + 1.0f) * 0.5f;
            slab[h] = cidx;
        }
    }
    __syncthreads();

    // --- phase 3: sim table, thread handles clusters {2p, 2p+1} of hierarchy h ---
    if (tid < HH * (NCN / 2)) {          // 375 tasks, waves 0..5
        int h = tid / (NCN / 2);
        int p = tid - h * (NCN / 2);
        const float2* ct  = (const float2*)(centT + h * (DD * NCN)) + p; // stride NCN/2 float2 per d
        const float4* sh4 = (const float4*)(sse + h * DD);
        float dA = 0.0f, dB = 0.0f;
        #pragma unroll 4
        for (int dq = 0; dq < DD / 4; ++dq) {
            float4 s4 = sh4[dq];
            float2 v0 = ct[0 * (NCN / 2)];
            float2 v1 = ct[1 * (NCN / 2)];
            float2 v2 = ct[2 * (NCN / 2)];
            float2 v3 = ct[3 * (NCN / 2)];
            ct += 4 * (NCN / 2);
            dA = fmaf(s4.x, v0.x, dA); dB = fmaf(s4.x, v0.y, dB);
            dA = fmaf(s4.y, v1.x, dA); dB = fmaf(s4.y, v1.y, dB);
            dA = fmaf(s4.z, v2.x, dA); dB = fmaf(s4.z, v2.y, dB);
            dA = fmaf(s4.w, v3.x, dA); dB = fmaf(s4.w, v3.y, dB);
        }
        ssim[h * NCN + 2 * p]     = (dA + 1.0f) * 0.5f;
        ssim[h * NCN + 2 * p + 1] = (dB + 1.0f) * 0.5f;
    }
    __syncthreads();

    // --- phase 4: negative-path loss ---
    int l0 = slab[0], l1 = slab[1], l2 = slab[2];
    float accL = 0.0f, accT = 0.0f;
    #pragma unroll
    for (int k = 0; k < NNEG / 512 + 1; ++k) {
        int n = tid + k * 512;
        if (n < NNEG) {
            int i0 = snegc[n * 3], i1 = snegc[n * 3 + 1], i2 = snegc[n * 3 + 2];
            float p = ssim[i0] * ssim[NCN + i1] * ssim[2 * NCN + i2];
            if (i0 != l0 || i1 != l1 || i2 != l2) {
                accL -= logf(1.0f - p + EPS);
                accT += 1.0f;
            }
        }
    }
    #pragma unroll
    for (int off = 32; off; off >>= 1) {
        accL += __shfl_xor(accL, off);
        accT += __shfl_xor(accT, off);
    }
    if (lane == 0) { wL[wave] = accL; wT[wave] = accT; }
    __syncthreads();

    // --- phase 5: combine + atomic ---
    if (tid == 0) {
        float L = 0.0f, T = 0.0f;
        #pragma unroll
        for (int w = 0; w < 8; ++w) { L += wL[w]; T += wT[w]; }
        float neg_b = L / (T + EPS);
        float pos_b = -logf(ph[0] * ph[1] * ph[2] + EPS);
        atomicAdd(out, (pos_b + neg_b) * (1.0f / (2.0f * BB)));
    }
}

extern "C" void kernel_launch(void* const* d_in, const int* in_sizes, int n_in,
                              void* d_out, int out_size, void* d_ws, size_t ws_size,
                              hipStream_t stream) {
    const float* se    = (const float*)d_in[0];
    const float* c0    = (const float*)d_in[1];
    const float* c1    = (const float*)d_in[2];
    const float* c2    = (const float*)d_in[3];
    const int*   i2c0  = (const int*)d_in[4];
    const int*   i2c1  = (const int*)d_in[5];
    const int*   i2c2  = (const int*)d_in[6];
    const int*   index = (const int*)d_in[7];
    const int*   negc  = (const int*)d_in[8];

    float* centT = (float*)d_ws;    // 96000 floats, [h][d][c]
    float* out   = (float*)d_out;

    hipLaunchKernelGGL(kA_prep, dim3((HH * NCN + 3) / 4), dim3(256), 0, stream,
                       c0, c1, c2, centT, out);
    hipLaunchKernelGGL(kB_main, dim3(BB), dim3(512), 0, stream,
                       se, c0, c1, c2, i2c0, i2c1, i2c2, index, negc, centT, out);
}